// Round 1
// baseline (2182.333 us; speedup 1.0000x reference)
//
#include <hip/hip_runtime.h>
#include <math.h>

// ---------------------------------------------------------------------------
// KimiDeltaAttention B=4 T=2048 HID=2048 H=16 DK=DV=128
//  - one fused QKV bf16 MFMA GEMM (N=6144) with silu+l2norm in epilogue
//  - one fused lowrank GEMM (fpre|gpre|beta, N=384 padded)
//  - scan v5: saddr+voffset addressing, volatile-asm loads with manual
//    vmcnt(24) 4-deep prefetch (32 loads in flight), asm o-store, no clamp
//    (bounded over-read inside allocated regions), drain before S_out.
// ---------------------------------------------------------------------------

typedef short short8 __attribute__((ext_vector_type(8)));
typedef float f32x4 __attribute__((ext_vector_type(4)));
typedef unsigned short ushort_t;

// gemm epilogue modes
enum { M_PLAIN = 0, M_QKV = 1, M_LOWRANK = 2, M_GATE = 3, M_FACTOR = 4 };

__device__ __forceinline__ unsigned short f32_to_bf16(float f) {
  unsigned int u = __float_as_uint(f);
  u += 0x7FFFu + ((u >> 16) & 1u);   // RNE
  return (unsigned short)(u >> 16);
}

__device__ __forceinline__ float silu(float x) { return x / (1.f + __expf(-x)); }

__device__ __forceinline__ void gld_lds16(const void* g, void* l) {
  __builtin_amdgcn_global_load_lds(
      (const __attribute__((address_space(1))) unsigned int*)g,
      (__attribute__((address_space(3))) unsigned int*)l, 16, 0, 0);
}

// sum across each aligned 16-lane group, pure DPP
__device__ __forceinline__ float row16_sum(float x) {
  x += __int_as_float(__builtin_amdgcn_update_dpp(0, __float_as_int(x), 0xB1, 0xF, 0xF, true));
  x += __int_as_float(__builtin_amdgcn_update_dpp(0, __float_as_int(x), 0x4E, 0xF, 0xF, true));
  x += __int_as_float(__builtin_amdgcn_update_dpp(0, __float_as_int(x), 0x141, 0xF, 0xF, true));
  x += __int_as_float(__builtin_amdgcn_update_dpp(0, __float_as_int(x), 0x140, 0xF, 0xF, true));
  return x;
}

// ---------------------------------------------------------------------------
// bf16 MFMA GEMM, 128x128 tile, m97 structure + mode-switched epilogue.
// ---------------------------------------------------------------------------
__global__ __launch_bounds__(256) void gemm_bf16(
    const ushort_t* __restrict__ A, const ushort_t* __restrict__ W,
    int M, int N, int K, int mode,
    float* __restrict__ f0, float* __restrict__ f1, float* __restrict__ f2,
    ushort_t* __restrict__ b0, ushort_t* __restrict__ b1,
    const float* __restrict__ bias, const float* __restrict__ A_log,
    const float* __restrict__ dt_bias) {
  __shared__ alignas(16) ushort_t As[4096];
  __shared__ alignas(16) ushort_t Bs[4096];
  __shared__ float l2s[2][128];
  const int tid = threadIdx.x;
  const int wv = tid >> 6, ln = tid & 63;
  const int bm = blockIdx.y * 128, bn = blockIdx.x * 128;
  const int wm = wv >> 1, wn = wv & 1;

  const int srow = tid >> 2;
  const int skg = (tid & 3) ^ ((srow >> 1) & 3);
  const size_t ag0 = (size_t)(bm + srow) * K + skg * 8;
  const size_t ag1 = ag0 + (size_t)64 * K;
  const size_t bg0 = (size_t)(bn + srow) * K + skg * 8;
  const size_t bg1 = bg0 + (size_t)64 * K;
  char* const lA = (char*)As;
  char* const lB = (char*)Bs;
  const int wbase = wv * 1024;

  const int fr = ln & 15, fq = ln >> 4;
  const int pg = fq ^ ((fr >> 1) & 3);
  int aoff[4], boff[4];
#pragma unroll
  for (int i = 0; i < 4; i++) {
    aoff[i] = (wm * 64 + i * 16 + fr) * 64 + pg * 16;
    boff[i] = (wn * 64 + i * 16 + fr) * 64 + pg * 16;
  }

  f32x4 acc[4][4];
#pragma unroll
  for (int i = 0; i < 4; i++)
#pragma unroll
    for (int j = 0; j < 4; j++) {
      acc[i][j][0] = 0.f; acc[i][j][1] = 0.f; acc[i][j][2] = 0.f; acc[i][j][3] = 0.f;
    }

  for (int k0 = 0; k0 < K; k0 += 32) {
    gld_lds16(A + ag0 + k0, lA + wbase);
    gld_lds16(A + ag1 + k0, lA + 4096 + wbase);
    gld_lds16(W + bg0 + k0, lB + wbase);
    gld_lds16(W + bg1 + k0, lB + 4096 + wbase);
    __syncthreads();
    short8 af[4], bf[4];
#pragma unroll
    for (int i = 0; i < 4; i++) af[i] = *(const short8*)(lA + aoff[i]);
#pragma unroll
    for (int i = 0; i < 4; i++) bf[i] = *(const short8*)(lB + boff[i]);
#pragma unroll
    for (int i = 0; i < 4; i++)
#pragma unroll
      for (int j = 0; j < 4; j++)
        acc[i][j] = __builtin_amdgcn_mfma_f32_16x16x32_bf16(af[i], bf[j], acc[i][j], 0, 0, 0);
    __syncthreads();
  }

  // C/D layout: col = ln&15, row = (ln>>4)*4 + reg
  const int cc = ln & 15, cq = ln >> 4;

  if (mode == M_QKV) {
    // silu in place
#pragma unroll
    for (int i = 0; i < 4; i++)
#pragma unroll
      for (int j = 0; j < 4; j++)
#pragma unroll
        for (int r = 0; r < 4; r++) acc[i][j][r] = silu(acc[i][j][r]);
    const bool isqk = (bn < 4096);
    float invr[4][4];
    if (isqk) {
      const float scale = (bn < 2048) ? 0.08838834764831845f : 1.0f;
#pragma unroll
      for (int i = 0; i < 4; i++)
#pragma unroll
        for (int r = 0; r < 4; r++) {
          float ss = 0.f;
#pragma unroll
          for (int j = 0; j < 4; j++) ss = fmaf(acc[i][j][r], acc[i][j][r], ss);
          ss = row16_sum(ss);
          if (cc == 0) l2s[wn][wm * 64 + i * 16 + cq * 4 + r] = ss;
        }
      __syncthreads();
#pragma unroll
      for (int i = 0; i < 4; i++)
#pragma unroll
        for (int r = 0; r < 4; r++) {
          const int rl = wm * 64 + i * 16 + cq * 4 + r;
          invr[i][r] = rsqrtf(l2s[0][rl] + l2s[1][rl] + 1e-6f) * scale;
        }
    } else {
#pragma unroll
      for (int i = 0; i < 4; i++)
#pragma unroll
        for (int r = 0; r < 4; r++) invr[i][r] = 1.f;
    }
    float* dst = (bn < 2048) ? f0 : ((bn < 4096) ? f1 : f2);
    const int nb = bn & 2047;
#pragma unroll
    for (int i = 0; i < 4; i++)
#pragma unroll
      for (int r = 0; r < 4; r++) {
        const int gm = bm + wm * 64 + i * 16 + cq * 4 + r;
#pragma unroll
        for (int j = 0; j < 4; j++) {
          const int gn = nb + wn * 64 + j * 16 + cc;
          dst[(size_t)gm * 2048 + gn] = acc[i][j][r] * invr[i][r];
        }
      }
    return;
  }

  if (mode == M_LOWRANK) {
#pragma unroll
    for (int i = 0; i < 4; i++)
#pragma unroll
      for (int r = 0; r < 4; r++) {
        const int gm = bm + wm * 64 + i * 16 + cq * 4 + r;
#pragma unroll
        for (int j = 0; j < 4; j++) {
          const int gn = bn + wn * 64 + j * 16 + cc;
          const float x = acc[i][j][r];
          if (gn < 128) b0[(size_t)gm * 128 + gn] = f32_to_bf16(x);
          else if (gn < 256) b1[(size_t)gm * 128 + (gn - 128)] = f32_to_bf16(x);
          else if (gn < 272) f0[(size_t)gm * 16 + (gn - 256)] = 1.f / (1.f + __expf(-x));
        }
      }
    return;
  }

  // M_PLAIN / M_GATE / M_FACTOR -> f32, stride N
#pragma unroll
  for (int i = 0; i < 4; i++)
#pragma unroll
    for (int r = 0; r < 4; r++) {
      const int gm = bm + wm * 64 + i * 16 + cq * 4 + r;
#pragma unroll
      for (int j = 0; j < 4; j++) {
        const int gn = bn + wn * 64 + j * 16 + cc;
        float x = acc[i][j][r];
        if (mode == M_FACTOR) x += bias[gn];
        else if (mode == M_GATE) {
          const float y = x + dt_bias[gn];
          const float sp = fmaxf(y, 0.f) + log1pf(__expf(-fabsf(y)));
          x = __expf(-__expf(A_log[gn >> 7]) * sp);
        }
        f0[(size_t)gm * N + gn] = x;
      }
    }
}

__global__ __launch_bounds__(256) void cast_bf16(const float* __restrict__ x,
                                                 ushort_t* __restrict__ y, int n) {
  const int i = (blockIdx.x * 256 + threadIdx.x) * 4;
  if (i >= n) return;
  const float4 v = *(const float4*)&x[i];
  union { ushort_t u[4]; uint2 v2; } o;
  o.u[0] = f32_to_bf16(v.x); o.u[1] = f32_to_bf16(v.y);
  o.u[2] = f32_to_bf16(v.z); o.u[3] = f32_to_bf16(v.w);
  *(uint2*)&y[i] = o.v2;
}

// ---------------------------------------------------------------------------
// Barrier-free gated delta-rule scan, v5.
// grid = 2048 (64 bh x 32 colgroups, XCD-swizzled), block = 64 (one wave).
// Lane: cl = ln>>4 (4 cols), kg = ln&15 (16-way k-split), S[8]/lane.
// All loop VMEM is volatile inline asm (saddr + 32-bit voffset); manual
// s_waitcnt vmcnt(24) keeps a true 4-slot (32-load) prefetch pipeline in
// flight. No clamp: trailing prefetches over-read <=32KB inside allocated
// workspace/output regions and are never consumed.
// ---------------------------------------------------------------------------
__global__ __launch_bounds__(64) void kda_scan(
    const float* __restrict__ q, const float* __restrict__ k,
    const float* __restrict__ v, const float* __restrict__ ge,
    const float* __restrict__ beta, const float* __restrict__ S0,
    float* __restrict__ o, float* __restrict__ S_out) {
  const int bid = blockIdx.x;
  const int bh = (((bid >> 3) & 7) << 3) | (bid & 7);
  const int cg = bid >> 6;
  const int h = bh & 15, b = bh >> 4;
  const int ln = threadIdx.x;
  const int cl = ln >> 4, kg = ln & 15;
  const int col = cg * 4 + cl;
  const int kof = kg * 8;

  const size_t s_base = (size_t)bh * (128 * 128);
  const size_t rb = (size_t)b * (2048 * 2048) + (size_t)h * 128;
  const size_t bbase = (size_t)(b * 2048) * 16 + h;

  // uniform SGPR bases per stream
  const float* kb  = k + rb;
  const float* qb  = q + rb;
  const float* gb  = ge + rb;
  const float* vb  = v + rb;
  const float* bb  = beta + bbase;
  float* obp       = o + rb;
  const float* S0b = S0 + s_base;

  // ---- initial state via asm loads (keeps compiler VMEM out of the loop) --
  float S[8];
#pragma unroll
  for (int j = 0; j < 8; ++j) {
    const unsigned offs = (unsigned)(((kof + j) * 128 + col) * 4);
    asm volatile("global_load_dword %0, %1, %2" : "=v"(S[j]) : "v"(offs), "s"(S0b));
  }
  asm volatile("s_waitcnt vmcnt(0)" ::: "memory");
  __builtin_amdgcn_sched_barrier(0);

  // ---- prefetch slots: 4 time-steps deep, 8 loads per slot ----------------
  f32x4 Ks0[4], Ks1[4], Qs0[4], Qs1[4], Gs0[4], Gs1[4];
  float Vs[4], Bs[4];
  unsigned voff   = (unsigned)(kof * 4);   // k/q/g share lane offset (bytes)
  unsigned voff_v = (unsigned)(col * 4);
  unsigned voff_b = 0u;
  unsigned voff_o = (unsigned)(col * 4);

#define KDA_PREFETCH(s)                                                                              \
  do {                                                                                               \
    asm volatile("global_load_dwordx4 %0, %1, %2"           : "=v"(Ks0[s]) : "v"(voff), "s"(kb));    \
    asm volatile("global_load_dwordx4 %0, %1, %2 offset:16" : "=v"(Ks1[s]) : "v"(voff), "s"(kb));    \
    asm volatile("global_load_dwordx4 %0, %1, %2"           : "=v"(Qs0[s]) : "v"(voff), "s"(qb));    \
    asm volatile("global_load_dwordx4 %0, %1, %2 offset:16" : "=v"(Qs1[s]) : "v"(voff), "s"(qb));    \
    asm volatile("global_load_dwordx4 %0, %1, %2"           : "=v"(Gs0[s]) : "v"(voff), "s"(gb));    \
    asm volatile("global_load_dwordx4 %0, %1, %2 offset:16" : "=v"(Gs1[s]) : "v"(voff), "s"(gb));    \
    asm volatile("global_load_dword %0, %1, %2"             : "=v"(Vs[s])  : "v"(voff_v), "s"(vb));  \
    asm volatile("global_load_dword %0, %1, %2"             : "=v"(Bs[s])  : "v"(voff_b), "s"(bb));  \
    voff += 8192u; voff_v += 8192u; voff_b += 64u;                                                   \
  } while (0)

  KDA_PREFETCH(0); KDA_PREFETCH(1); KDA_PREFETCH(2); KDA_PREFETCH(3);

  // step: wait slot, compute, store o, refill slot for t+4.
  // vmcnt(24): 32 loads + (<=3) stores outstanding before the wait; keeping
  // <=24 newest guarantees this slot's 8 loads have returned.
#define KDA_STEP(s)                                                                                  \
  do {                                                                                               \
    asm volatile("s_waitcnt vmcnt(24)" ::: "memory");                                                \
    __builtin_amdgcn_sched_barrier(0);                                                               \
    float p0 = 0.f, p1 = 0.f, o0 = 0.f, o1 = 0.f, d0 = 0.f, d1 = 0.f;                                \
    S[0] *= Gs0[s].x; p0 = fmaf(Ks0[s].x, S[0], p0); o0 = fmaf(Qs0[s].x, S[0], o0); d0 = fmaf(Qs0[s].x, Ks0[s].x, d0); \
    S[1] *= Gs0[s].y; p1 = fmaf(Ks0[s].y, S[1], p1); o1 = fmaf(Qs0[s].y, S[1], o1); d1 = fmaf(Qs0[s].y, Ks0[s].y, d1); \
    S[2] *= Gs0[s].z; p0 = fmaf(Ks0[s].z, S[2], p0); o0 = fmaf(Qs0[s].z, S[2], o0); d0 = fmaf(Qs0[s].z, Ks0[s].z, d0); \
    S[3] *= Gs0[s].w; p1 = fmaf(Ks0[s].w, S[3], p1); o1 = fmaf(Qs0[s].w, S[3], o1); d1 = fmaf(Qs0[s].w, Ks0[s].w, d1); \
    S[4] *= Gs1[s].x; p0 = fmaf(Ks1[s].x, S[4], p0); o0 = fmaf(Qs1[s].x, S[4], o0); d0 = fmaf(Qs1[s].x, Ks1[s].x, d0); \
    S[5] *= Gs1[s].y; p1 = fmaf(Ks1[s].y, S[5], p1); o1 = fmaf(Qs1[s].y, S[5], o1); d1 = fmaf(Qs1[s].y, Ks1[s].y, d1); \
    S[6] *= Gs1[s].z; p0 = fmaf(Ks1[s].z, S[6], p0); o0 = fmaf(Qs1[s].z, S[6], o0); d0 = fmaf(Qs1[s].z, Ks1[s].z, d0); \
    S[7] *= Gs1[s].w; p1 = fmaf(Ks1[s].w, S[7], p1); o1 = fmaf(Qs1[s].w, S[7], o1); d1 = fmaf(Qs1[s].w, Ks1[s].w, d1); \
    const float p  = row16_sum(p0 + p1);                                                             \
    const float oq = row16_sum(o0 + o1);                                                             \
    const float qk = row16_sum(d0 + d1);                                                             \
    const float delta = (Vs[s] - p) * Bs[s];                                                         \
    const float op = fmaf(qk, delta, oq);                                                            \
    if (kg == 0)                                                                                     \
      asm volatile("global_store_dword %0, %1, %2" :: "v"(voff_o), "v"(op), "s"(obp) : "memory");    \
    voff_o += 8192u;                                                                                 \
    S[0] = fmaf(Ks0[s].x, delta, S[0]);                                                              \
    S[1] = fmaf(Ks0[s].y, delta, S[1]);                                                              \
    S[2] = fmaf(Ks0[s].z, delta, S[2]);                                                              \
    S[3] = fmaf(Ks0[s].w, delta, S[3]);                                                              \
    S[4] = fmaf(Ks1[s].x, delta, S[4]);                                                              \
    S[5] = fmaf(Ks1[s].y, delta, S[5]);                                                              \
    S[6] = fmaf(Ks1[s].z, delta, S[6]);                                                              \
    S[7] = fmaf(Ks1[s].w, delta, S[7]);                                                              \
    KDA_PREFETCH(s);                                                                                 \
  } while (0)

  for (int it = 0; it < 512; ++it) {
    KDA_STEP(0);
    KDA_STEP(1);
    KDA_STEP(2);
    KDA_STEP(3);
  }

  // drain all outstanding asm loads before reusing VGPRs / ending the wave
  asm volatile("s_waitcnt vmcnt(0)" ::: "memory");
  __builtin_amdgcn_sched_barrier(0);

#pragma unroll
  for (int j = 0; j < 8; ++j)
    S_out[s_base + (size_t)(kof + j) * 128 + col] = S[j];
#undef KDA_STEP
#undef KDA_PREFETCH
}

// out_bf16 = rms(o)*w*sigmoid(factor). grid 2048 x 256: 64 rows/block.
__global__ __launch_bounds__(256) void gate_rmsnorm(
    const float* __restrict__ o, const float* __restrict__ factor,
    const float* __restrict__ w, ushort_t* __restrict__ out) {
  const int ln = threadIdx.x & 63, wv = threadIdx.x >> 6;
  const float w0 = w[ln * 2], w1 = w[ln * 2 + 1];
  const size_t row0 = (size_t)blockIdx.x * 64 + wv * 16;
  for (int it = 0; it < 16; it++) {
    const size_t base = (row0 + it) * 128 + ln * 2;
    const float2 x = *(const float2*)&o[base];
    const float2 f = *(const float2*)&factor[base];
    float ss = fmaf(x.x, x.x, x.y * x.y);
    ss = row16_sum(ss);
    ss += __shfl_xor(ss, 16);
    ss += __shfl_xor(ss, 32);
    const float r = rsqrtf(ss * (1.f / 128.f) + 1e-5f);
    const float y0 = x.x * r * w0 / (1.f + __expf(-f.x));
    const float y1 = x.y * r * w1 / (1.f + __expf(-f.y));
    *(unsigned int*)&out[base] =
        (unsigned int)f32_to_bf16(y0) | ((unsigned int)f32_to_bf16(y1) << 16);
  }
}

extern "C" void kernel_launch(void* const* d_in, const int* in_sizes, int n_in,
                              void* d_out, int out_size, void* d_ws, size_t ws_size,
                              hipStream_t stream) {
  const float* h    = (const float*)d_in[0];
  const float* S0   = (const float*)d_in[1];
  const float* q_w  = (const float*)d_in[2];
  const float* k_w  = (const float*)d_in[3];
  const float* v_w  = (const float*)d_in[4];
  const float* f_w0 = (const float*)d_in[5];
  const float* f_w1 = (const float*)d_in[6];
  const float* b_w  = (const float*)d_in[7];
  const float* A_log  = (const float*)d_in[8];
  const float* dt_b   = (const float*)d_in[9];
  const float* g_w0 = (const float*)d_in[10];
  const float* g_w1 = (const float*)d_in[11];
  const float* g_b1 = (const float*)d_in[12];
  const float* o_nw = (const float*)d_in[13];
  const float* o_w  = (const float*)d_in[14];

  float* outp = (float*)d_out;                 // exp(g) -> factor -> final out
  float* Sout = outp + (size_t)8192 * 2048;

  const size_t BIG = (size_t)8192 * 2048;   // 16.8M elems
  float* ws = (float*)d_ws;
  float* vbuf  = ws;                         // f32 [BIG]
  float* qbuf  = vbuf + BIG;                 // f32 [BIG]; gated bf16 reuses this
  float* kbuf  = qbuf + BIG;                 // f32 [BIG]
  float* betab = kbuf + BIG;                 // f32 [8192*16]
  ushort_t* fpreb = (ushort_t*)(betab + (size_t)8192 * 16);   // bf16 [8192*128]
  ushort_t* gpreb = fpreb + (size_t)8192 * 128;
  ushort_t* wf1   = gpreb + (size_t)8192 * 128;               // [2048*128]
  ushort_t* wg1   = wf1 + (size_t)2048 * 128;
  ushort_t* wo    = wg1 + (size_t)2048 * 128;                 // [2048*2048]
  ushort_t* wlow  = wo + (size_t)2048 * 2048;                 // [384*2048]
  ushort_t* hb    = wlow + (size_t)384 * 2048;                // [BIG] bf16
  ushort_t* wqkv  = hb + BIG;                                 // [6144*2048] bf16
  // obuf (scan output, f32 BIG) aliases [hb | wqkv | pad] — all dead pre-scan
  float* obuf = (float*)hb;
  ushort_t* gatedb = (ushort_t*)qbuf;        // bf16 gated o (qbuf dead post-scan)

  const dim3 blk(256);

  // casts
  cast_bf16<<<16384, blk, 0, stream>>>(h, hb, 8192 * 2048);
  cast_bf16<<<4096, blk, 0, stream>>>(q_w, wqkv, 2048 * 2048);
  cast_bf16<<<4096, blk, 0, stream>>>(k_w, wqkv + (size_t)2048 * 2048, 2048 * 2048);
  cast_bf16<<<4096, blk, 0, stream>>>(v_w, wqkv + (size_t)4096 * 2048, 2048 * 2048);
  cast_bf16<<<4096, blk, 0, stream>>>(o_w, wo, 2048 * 2048);
  cast_bf16<<<256, blk, 0, stream>>>(f_w0, wlow, 128 * 2048);
  cast_bf16<<<256, blk, 0, stream>>>(g_w0, wlow + (size_t)128 * 2048, 128 * 2048);
  cast_bf16<<<32, blk, 0, stream>>>(b_w, wlow + (size_t)256 * 2048, 16 * 2048);
  cast_bf16<<<256, blk, 0, stream>>>(f_w1, wf1, 2048 * 128);
  cast_bf16<<<256, blk, 0, stream>>>(g_w1, wg1, 2048 * 128);

  // fused QKV projection: silu(+l2norm for q/k) -> qbuf/kbuf/vbuf f32
  gemm_bf16<<<dim3(48, 64), blk, 0, stream>>>(hb, wqkv, 8192, 6144, 2048, M_QKV,
      qbuf, kbuf, vbuf, nullptr, nullptr, nullptr, nullptr, nullptr);
  // fused lowrank: fpre|gpre (bf16) + beta (sigmoid f32)
  gemm_bf16<<<dim3(3, 64), blk, 0, stream>>>(hb, wlow, 8192, 384, 2048, M_LOWRANK,
      betab, nullptr, nullptr, fpreb, gpreb, nullptr, nullptr, nullptr);
  // exp(g) -> outp
  gemm_bf16<<<dim3(16, 64), blk, 0, stream>>>(fpreb, wf1, 8192, 2048, 128, M_GATE,
      outp, nullptr, nullptr, nullptr, nullptr, nullptr, A_log, dt_b);
  // scan: o -> obuf (hb/wqkv region dead), S -> d_out tail
  kda_scan<<<2048, 64, 0, stream>>>(qbuf, kbuf, vbuf, outp, betab, S0, obuf, Sout);
  // factor = gpre @ g_w1.T + g_b1 -> outp (exp(g) dead)
  gemm_bf16<<<dim3(16, 64), blk, 0, stream>>>(gpreb, wg1, 8192, 2048, 128, M_FACTOR,
      outp, nullptr, nullptr, nullptr, nullptr, g_b1, nullptr, nullptr);
  // gated rmsnorm -> bf16 into gatedb (qbuf region)
  gate_rmsnorm<<<2048, blk, 0, stream>>>(obuf, outp, o_nw, gatedb);
  // out = gated_o @ o_w.T -> outp
  gemm_bf16<<<dim3(16, 64), blk, 0, stream>>>(gatedb, wo, 8192, 2048, 2048, M_PLAIN,
      outp, nullptr, nullptr, nullptr, nullptr, nullptr, nullptr, nullptr);
}

// Round 2
// 1853.181 us; speedup vs baseline: 1.1776x; 1.1776x over previous
//
#include <hip/hip_runtime.h>
#include <math.h>

// ---------------------------------------------------------------------------
// KimiDeltaAttention B=4 T=2048 HID=2048 H=16 DK=DV=128
//  - one fused QKV bf16 MFMA GEMM (N=6144) with silu+l2norm in epilogue
//  - one fused lowrank GEMM (fpre|gpre|beta, N=384 padded)
//  - scan v6: k/q/g staged via global_load_lds (1KB = 2 steps/stream, no lane
//    duplication), 4 LDS slots = 8-step prefetch horizon, swizzled
//    ds_read_b128 fragments (2-way bank alias = free), ds-reads pipelined one
//    step ahead (lgkmcnt(6)), o-stores batched after restage, uniform
//    vmcnt(20) steady-state counted waits. v/beta via direct asm loads.
// ---------------------------------------------------------------------------

typedef short short8 __attribute__((ext_vector_type(8)));
typedef float f32x4 __attribute__((ext_vector_type(4)));
typedef unsigned short ushort_t;

// gemm epilogue modes
enum { M_PLAIN = 0, M_QKV = 1, M_LOWRANK = 2, M_GATE = 3, M_FACTOR = 4 };

__device__ __forceinline__ unsigned short f32_to_bf16(float f) {
  unsigned int u = __float_as_uint(f);
  u += 0x7FFFu + ((u >> 16) & 1u);   // RNE
  return (unsigned short)(u >> 16);
}

__device__ __forceinline__ float silu(float x) { return x / (1.f + __expf(-x)); }

__device__ __forceinline__ void gld_lds16(const void* g, void* l) {
  __builtin_amdgcn_global_load_lds(
      (const __attribute__((address_space(1))) unsigned int*)g,
      (__attribute__((address_space(3))) unsigned int*)l, 16, 0, 0);
}

// sum across each aligned 16-lane group, pure DPP
__device__ __forceinline__ float row16_sum(float x) {
  x += __int_as_float(__builtin_amdgcn_update_dpp(0, __float_as_int(x), 0xB1, 0xF, 0xF, true));
  x += __int_as_float(__builtin_amdgcn_update_dpp(0, __float_as_int(x), 0x4E, 0xF, 0xF, true));
  x += __int_as_float(__builtin_amdgcn_update_dpp(0, __float_as_int(x), 0x141, 0xF, 0xF, true));
  x += __int_as_float(__builtin_amdgcn_update_dpp(0, __float_as_int(x), 0x140, 0xF, 0xF, true));
  return x;
}

// ---------------------------------------------------------------------------
// bf16 MFMA GEMM, 128x128 tile, m97 structure + mode-switched epilogue.
// ---------------------------------------------------------------------------
__global__ __launch_bounds__(256) void gemm_bf16(
    const ushort_t* __restrict__ A, const ushort_t* __restrict__ W,
    int M, int N, int K, int mode,
    float* __restrict__ f0, float* __restrict__ f1, float* __restrict__ f2,
    ushort_t* __restrict__ b0, ushort_t* __restrict__ b1,
    const float* __restrict__ bias, const float* __restrict__ A_log,
    const float* __restrict__ dt_bias) {
  __shared__ alignas(16) ushort_t As[4096];
  __shared__ alignas(16) ushort_t Bs[4096];
  __shared__ float l2s[2][128];
  const int tid = threadIdx.x;
  const int wv = tid >> 6, ln = tid & 63;
  const int bm = blockIdx.y * 128, bn = blockIdx.x * 128;
  const int wm = wv >> 1, wn = wv & 1;

  const int srow = tid >> 2;
  const int skg = (tid & 3) ^ ((srow >> 1) & 3);
  const size_t ag0 = (size_t)(bm + srow) * K + skg * 8;
  const size_t ag1 = ag0 + (size_t)64 * K;
  const size_t bg0 = (size_t)(bn + srow) * K + skg * 8;
  const size_t bg1 = bg0 + (size_t)64 * K;
  char* const lA = (char*)As;
  char* const lB = (char*)Bs;
  const int wbase = wv * 1024;

  const int fr = ln & 15, fq = ln >> 4;
  const int pg = fq ^ ((fr >> 1) & 3);
  int aoff[4], boff[4];
#pragma unroll
  for (int i = 0; i < 4; i++) {
    aoff[i] = (wm * 64 + i * 16 + fr) * 64 + pg * 16;
    boff[i] = (wn * 64 + i * 16 + fr) * 64 + pg * 16;
  }

  f32x4 acc[4][4];
#pragma unroll
  for (int i = 0; i < 4; i++)
#pragma unroll
    for (int j = 0; j < 4; j++) {
      acc[i][j][0] = 0.f; acc[i][j][1] = 0.f; acc[i][j][2] = 0.f; acc[i][j][3] = 0.f;
    }

  for (int k0 = 0; k0 < K; k0 += 32) {
    gld_lds16(A + ag0 + k0, lA + wbase);
    gld_lds16(A + ag1 + k0, lA + 4096 + wbase);
    gld_lds16(W + bg0 + k0, lB + wbase);
    gld_lds16(W + bg1 + k0, lB + 4096 + wbase);
    __syncthreads();
    short8 af[4], bf[4];
#pragma unroll
    for (int i = 0; i < 4; i++) af[i] = *(const short8*)(lA + aoff[i]);
#pragma unroll
    for (int i = 0; i < 4; i++) bf[i] = *(const short8*)(lB + boff[i]);
#pragma unroll
    for (int i = 0; i < 4; i++)
#pragma unroll
      for (int j = 0; j < 4; j++)
        acc[i][j] = __builtin_amdgcn_mfma_f32_16x16x32_bf16(af[i], bf[j], acc[i][j], 0, 0, 0);
    __syncthreads();
  }

  // C/D layout: col = ln&15, row = (ln>>4)*4 + reg
  const int cc = ln & 15, cq = ln >> 4;

  if (mode == M_QKV) {
    // silu in place
#pragma unroll
    for (int i = 0; i < 4; i++)
#pragma unroll
      for (int j = 0; j < 4; j++)
#pragma unroll
        for (int r = 0; r < 4; r++) acc[i][j][r] = silu(acc[i][j][r]);
    const bool isqk = (bn < 4096);
    float invr[4][4];
    if (isqk) {
      const float scale = (bn < 2048) ? 0.08838834764831845f : 1.0f;
#pragma unroll
      for (int i = 0; i < 4; i++)
#pragma unroll
        for (int r = 0; r < 4; r++) {
          float ss = 0.f;
#pragma unroll
          for (int j = 0; j < 4; j++) ss = fmaf(acc[i][j][r], acc[i][j][r], ss);
          ss = row16_sum(ss);
          if (cc == 0) l2s[wn][wm * 64 + i * 16 + cq * 4 + r] = ss;
        }
      __syncthreads();
#pragma unroll
      for (int i = 0; i < 4; i++)
#pragma unroll
        for (int r = 0; r < 4; r++) {
          const int rl = wm * 64 + i * 16 + cq * 4 + r;
          invr[i][r] = rsqrtf(l2s[0][rl] + l2s[1][rl] + 1e-6f) * scale;
        }
    } else {
#pragma unroll
      for (int i = 0; i < 4; i++)
#pragma unroll
        for (int r = 0; r < 4; r++) invr[i][r] = 1.f;
    }
    float* dst = (bn < 2048) ? f0 : ((bn < 4096) ? f1 : f2);
    const int nb = bn & 2047;
#pragma unroll
    for (int i = 0; i < 4; i++)
#pragma unroll
      for (int r = 0; r < 4; r++) {
        const int gm = bm + wm * 64 + i * 16 + cq * 4 + r;
#pragma unroll
        for (int j = 0; j < 4; j++) {
          const int gn = nb + wn * 64 + j * 16 + cc;
          dst[(size_t)gm * 2048 + gn] = acc[i][j][r] * invr[i][r];
        }
      }
    return;
  }

  if (mode == M_LOWRANK) {
#pragma unroll
    for (int i = 0; i < 4; i++)
#pragma unroll
      for (int r = 0; r < 4; r++) {
        const int gm = bm + wm * 64 + i * 16 + cq * 4 + r;
#pragma unroll
        for (int j = 0; j < 4; j++) {
          const int gn = bn + wn * 64 + j * 16 + cc;
          const float x = acc[i][j][r];
          if (gn < 128) b0[(size_t)gm * 128 + gn] = f32_to_bf16(x);
          else if (gn < 256) b1[(size_t)gm * 128 + (gn - 128)] = f32_to_bf16(x);
          else if (gn < 272) f0[(size_t)gm * 16 + (gn - 256)] = 1.f / (1.f + __expf(-x));
        }
      }
    return;
  }

  // M_PLAIN / M_GATE / M_FACTOR -> f32, stride N
#pragma unroll
  for (int i = 0; i < 4; i++)
#pragma unroll
    for (int r = 0; r < 4; r++) {
      const int gm = bm + wm * 64 + i * 16 + cq * 4 + r;
#pragma unroll
      for (int j = 0; j < 4; j++) {
        const int gn = bn + wn * 64 + j * 16 + cc;
        float x = acc[i][j][r];
        if (mode == M_FACTOR) x += bias[gn];
        else if (mode == M_GATE) {
          const float y = x + dt_bias[gn];
          const float sp = fmaxf(y, 0.f) + log1pf(__expf(-fabsf(y)));
          x = __expf(-__expf(A_log[gn >> 7]) * sp);
        }
        f0[(size_t)gm * N + gn] = x;
      }
    }
}

__global__ __launch_bounds__(256) void cast_bf16(const float* __restrict__ x,
                                                 ushort_t* __restrict__ y, int n) {
  const int i = (blockIdx.x * 256 + threadIdx.x) * 4;
  if (i >= n) return;
  const float4 v = *(const float4*)&x[i];
  union { ushort_t u[4]; uint2 v2; } o;
  o.u[0] = f32_to_bf16(v.x); o.u[1] = f32_to_bf16(v.y);
  o.u[2] = f32_to_bf16(v.z); o.u[3] = f32_to_bf16(v.w);
  *(uint2*)&y[i] = o.v2;
}

// ---------------------------------------------------------------------------
// Barrier-free gated delta-rule scan, v6. LDS-staged k/q/g.
// grid = 2048 (64 bh x 32 colgroups, XCD-swizzled), block = 64 (one wave).
// Lane: cl = ln>>4 (4 cols), kg = ln&15 (16-way k-split), S[8]/lane.
// LDS: 4 slots x 3 streams x 1KB (2 steps/slot) = 12KB, 8-step prefetch.
// Stage: 3 global_load_lds_dwordx4 per 2 steps (no lane duplication).
// Read: 6 ds_read_b128/step, chunk-swizzled (bit3->bit0 XOR) for 2-way banks.
// ds-reads issued 1 step ahead (lgkmcnt(6)); o-stores batched after restage;
// counted vmcnt: 14/16/18/20 peel then uniform 20. sched_barrier after waits.
// ---------------------------------------------------------------------------
__global__ __launch_bounds__(64, 2) void kda_scan(
    const float* __restrict__ q, const float* __restrict__ k,
    const float* __restrict__ v, const float* __restrict__ ge,
    const float* __restrict__ beta, const float* __restrict__ S0,
    float* __restrict__ o, float* __restrict__ S_out) {
  const int bid = blockIdx.x;
  const int bh = (((bid >> 3) & 7) << 3) | (bid & 7);
  const int cg = bid >> 6;
  const int h = bh & 15, b = bh >> 4;
  const int ln = threadIdx.x;
  const int cl = ln >> 4, kg = ln & 15;
  const int col = cg * 4 + cl;
  const int kof = kg * 8;

  __shared__ alignas(16) char lds[12288];

  const size_t s_base = (size_t)bh * (128 * 128);
  const size_t rb = (size_t)b * (2048 * 2048) + (size_t)h * 128;
  const size_t bbase = (size_t)(b * 2048) * 16 + h;

  const char* kc = (const char*)(k + rb);
  const char* qc = (const char*)(q + rb);
  const char* gc = (const char*)(ge + rb);
  const float* vb = v + rb;
  const float* bb = beta + bbase;
  float* obp = o + rb;
  const float* S0b = S0 + s_base;

  // per-lane gld_lds SOURCE pre-swizzle (LDS dest is linear lane*16):
  // LDS chunk p holds global chunk g(p) = (p&~1)|((p&1)^((p>>3)&1))
  const int cpos = ln & 31;
  const int gch = (cpos & ~1) | ((cpos & 1) ^ ((cpos >> 3) & 1));
  const unsigned lane_src = (unsigned)((ln >> 5) * 8192 + gch * 16);

  // swizzled ds_read addresses for logical chunks q=0,1 of this lane's kg
  const unsigned rd0 = (unsigned)(kg * 32 + ((0 ^ ((kg >> 2) & 1)) * 16));
  const unsigned rd1 = (unsigned)(kg * 32 + ((1 ^ ((kg >> 2) & 1)) * 16));

  // ---- initial state via asm loads ----------------------------------------
  float S[8];
#pragma unroll
  for (int j = 0; j < 8; ++j) {
    const unsigned offs = (unsigned)(((kof + j) * 128 + col) * 4);
    asm volatile("global_load_dword %0, %1, %2" : "=v"(S[j]) : "v"(offs), "s"(S0b));
  }

  float Vs[8], Bs[8], Os[8];
  f32x4 K0a, K1a, Q0a, Q1a, G0a, G1a;
  f32x4 K0b, K1b, Q0b, Q1b, G0b, G1b;
  unsigned voff_v = (unsigned)(col * 4);
  unsigned voff_b = 0u;
  unsigned voff_o = (unsigned)(col * 4);

#define WAITV(N) do { asm volatile("s_waitcnt vmcnt(" #N ")" ::: "memory"); \
                      __builtin_amdgcn_sched_barrier(0); } while (0)
#define WAITL(N) do { asm volatile("s_waitcnt lgkmcnt(" #N ")" ::: "memory"); \
                      __builtin_amdgcn_sched_barrier(0); } while (0)
#define DSR(dst, a, IMM) \
  asm volatile("ds_read_b128 %0, %1 offset:%c2" : "=v"(dst) : "v"(a), "n"(IMM))

// 6 ds_reads for one step: slot SL, phase PH, into buffer suffix SFX
#define READS(SFX, SL, PH)                                    \
  do {                                                        \
    DSR(K0##SFX, rd0, ((SL)*3 + 0) * 1024 + (PH)*512);        \
    DSR(K1##SFX, rd1, ((SL)*3 + 0) * 1024 + (PH)*512);        \
    DSR(Q0##SFX, rd0, ((SL)*3 + 1) * 1024 + (PH)*512);        \
    DSR(Q1##SFX, rd1, ((SL)*3 + 1) * 1024 + (PH)*512);        \
    DSR(G0##SFX, rd0, ((SL)*3 + 2) * 1024 + (PH)*512);        \
    DSR(G1##SFX, rd1, ((SL)*3 + 2) * 1024 + (PH)*512);        \
  } while (0)

// stage slot SL from byte offset BOFF (rows BOFF/8192, BOFF/8192+1): 7 VMEM ops
#define STAGE(SL, BOFF)                                                                              \
  do {                                                                                               \
    gld_lds16(kc + (BOFF) + lane_src, lds + ((SL)*3 + 0) * 1024);                                    \
    gld_lds16(qc + (BOFF) + lane_src, lds + ((SL)*3 + 1) * 1024);                                    \
    gld_lds16(gc + (BOFF) + lane_src, lds + ((SL)*3 + 2) * 1024);                                    \
    asm volatile("global_load_dword %0, %1, %2" : "=v"(Vs[2*(SL)])   : "v"(voff_v), "s"(vb));        \
    voff_v += 8192u;                                                                                 \
    asm volatile("global_load_dword %0, %1, %2" : "=v"(Vs[2*(SL)+1]) : "v"(voff_v), "s"(vb));        \
    voff_v += 8192u;                                                                                 \
    asm volatile("global_load_dword %0, %1, %2" : "=v"(Bs[2*(SL)])   : "v"(voff_b), "s"(bb));        \
    voff_b += 64u;                                                                                   \
    asm volatile("global_load_dword %0, %1, %2" : "=v"(Bs[2*(SL)+1]) : "v"(voff_b), "s"(bb));        \
    voff_b += 64u;                                                                                   \
  } while (0)

#define STORES(U)                                                                                    \
  do {                                                                                               \
    if (kg == 0)                                                                                     \
      asm volatile("global_store_dword %0, %1, %2" :: "v"(voff_o), "v"(Os[(U)-1]), "s"(obp) : "memory"); \
    voff_o += 8192u;                                                                                 \
    if (kg == 0)                                                                                     \
      asm volatile("global_store_dword %0, %1, %2" :: "v"(voff_o), "v"(Os[(U)]), "s"(obp) : "memory");   \
    voff_o += 8192u;                                                                                 \
  } while (0)

#define COMPUTE(SFX, U)                                                                              \
  do {                                                                                               \
    float p0 = 0.f, p1 = 0.f, o0 = 0.f, o1 = 0.f, d0 = 0.f, d1 = 0.f;                                \
    S[0] *= G0##SFX[0]; p0 = fmaf(K0##SFX[0], S[0], p0); o0 = fmaf(Q0##SFX[0], S[0], o0); d0 = fmaf(Q0##SFX[0], K0##SFX[0], d0); \
    S[1] *= G0##SFX[1]; p1 = fmaf(K0##SFX[1], S[1], p1); o1 = fmaf(Q0##SFX[1], S[1], o1); d1 = fmaf(Q0##SFX[1], K0##SFX[1], d1); \
    S[2] *= G0##SFX[2]; p0 = fmaf(K0##SFX[2], S[2], p0); o0 = fmaf(Q0##SFX[2], S[2], o0); d0 = fmaf(Q0##SFX[2], K0##SFX[2], d0); \
    S[3] *= G0##SFX[3]; p1 = fmaf(K0##SFX[3], S[3], p1); o1 = fmaf(Q0##SFX[3], S[3], o1); d1 = fmaf(Q0##SFX[3], K0##SFX[3], d1); \
    S[4] *= G1##SFX[0]; p0 = fmaf(K1##SFX[0], S[4], p0); o0 = fmaf(Q1##SFX[0], S[4], o0); d0 = fmaf(Q1##SFX[0], K1##SFX[0], d0); \
    S[5] *= G1##SFX[1]; p1 = fmaf(K1##SFX[1], S[5], p1); o1 = fmaf(Q1##SFX[1], S[5], o1); d1 = fmaf(Q1##SFX[1], K1##SFX[1], d1); \
    S[6] *= G1##SFX[2]; p0 = fmaf(K1##SFX[2], S[6], p0); o0 = fmaf(Q1##SFX[2], S[6], o0); d0 = fmaf(Q1##SFX[2], K1##SFX[2], d0); \
    S[7] *= G1##SFX[3]; p1 = fmaf(K1##SFX[3], S[7], p1); o1 = fmaf(Q1##SFX[3], S[7], o1); d1 = fmaf(Q1##SFX[3], K1##SFX[3], d1); \
    const float p  = row16_sum(p0 + p1);                                                             \
    const float oq = row16_sum(o0 + o1);                                                             \
    const float qk = row16_sum(d0 + d1);                                                             \
    const float delta = (Vs[(U)] - p) * Bs[(U)];                                                     \
    Os[(U)] = fmaf(qk, delta, oq);                                                                   \
    S[0] = fmaf(K0##SFX[0], delta, S[0]);                                                            \
    S[1] = fmaf(K0##SFX[1], delta, S[1]);                                                            \
    S[2] = fmaf(K0##SFX[2], delta, S[2]);                                                            \
    S[3] = fmaf(K0##SFX[3], delta, S[3]);                                                            \
    S[4] = fmaf(K1##SFX[0], delta, S[4]);                                                            \
    S[5] = fmaf(K1##SFX[1], delta, S[5]);                                                            \
    S[6] = fmaf(K1##SFX[2], delta, S[6]);                                                            \
    S[7] = fmaf(K1##SFX[3], delta, S[7]);                                                            \
  } while (0)

// even step U (slot SL): issue reads for U+1 (phase 1), compute U from 'a'
#define STEP_EVEN(U, SL) \
  do { READS(b, SL, 1); WAITL(6); COMPUTE(a, U); } while (0)
// odd step U (slot SL): wait next slot NSL, issue its phase-0 reads, compute
// U from 'b', restage SL for +8, batch-store Os[U-1],Os[U]
#define STEP_ODD(U, SL, NSL, WV, BOFF) \
  do { WAITV(WV); READS(a, NSL, 0); WAITL(6); COMPUTE(b, U); STAGE(SL, BOFF); STORES(U); } while (0)

#define ITER(W1, W3, W5, W7)                          \
  do {                                                \
    STEP_EVEN(0, 0);                                  \
    STEP_ODD(1, 0, 1, W1, adv + 0 * 16384);           \
    STEP_EVEN(2, 1);                                  \
    STEP_ODD(3, 1, 2, W3, adv + 1 * 16384);           \
    STEP_EVEN(4, 2);                                  \
    STEP_ODD(5, 2, 3, W5, adv + 2 * 16384);           \
    STEP_EVEN(6, 3);                                  \
    STEP_ODD(7, 3, 0, W7, adv + 3 * 16384);           \
  } while (0)

  // ---- prologue: stage slots 0..3 (steps 0..7), wait slot0, prime reads ---
  STAGE(0, (size_t)0 * 16384);
  STAGE(1, (size_t)1 * 16384);
  STAGE(2, (size_t)2 * 16384);
  STAGE(3, (size_t)3 * 16384);
  WAITV(21);               // drains S0(8)+slot0(7); keeps slots 1-3 (21)
  READS(a, 0, 0);          // step 0 fragments

  size_t adv = 65536;      // byte offset of row (base+8); base=0 for iter 0
  ITER(14, 16, 18, 20);    // peeled first iteration (prologue FIFO spacing)
  adv += 65536;
  for (int it = 1; it < 256; ++it) {
    ITER(20, 20, 20, 20);
    adv += 65536;
  }
  // final iteration's restages/reads over-run into adjacent allocated
  // workspace/output regions (<=16KB) and are never consumed.

  // drain everything before the compiler may reuse destination VGPRs
  WAITL(0);
  WAITV(0);

#pragma unroll
  for (int j = 0; j < 8; ++j)
    S_out[s_base + (size_t)(kof + j) * 128 + col] = S[j];

#undef ITER
#undef STEP_ODD
#undef STEP_EVEN
#undef COMPUTE
#undef STORES
#undef STAGE
#undef READS
#undef DSR
#undef WAITL
#undef WAITV
}

// out_bf16 = rms(o)*w*sigmoid(factor). grid 2048 x 256: 64 rows/block.
__global__ __launch_bounds__(256) void gate_rmsnorm(
    const float* __restrict__ o, const float* __restrict__ factor,
    const float* __restrict__ w, ushort_t* __restrict__ out) {
  const int ln = threadIdx.x & 63, wv = threadIdx.x >> 6;
  const float w0 = w[ln * 2], w1 = w[ln * 2 + 1];
  const size_t row0 = (size_t)blockIdx.x * 64 + wv * 16;
  for (int it = 0; it < 16; it++) {
    const size_t base = (row0 + it) * 128 + ln * 2;
    const float2 x = *(const float2*)&o[base];
    const float2 f = *(const float2*)&factor[base];
    float ss = fmaf(x.x, x.x, x.y * x.y);
    ss = row16_sum(ss);
    ss += __shfl_xor(ss, 16);
    ss += __shfl_xor(ss, 32);
    const float r = rsqrtf(ss * (1.f / 128.f) + 1e-5f);
    const float y0 = x.x * r * w0 / (1.f + __expf(-f.x));
    const float y1 = x.y * r * w1 / (1.f + __expf(-f.y));
    *(unsigned int*)&out[base] =
        (unsigned int)f32_to_bf16(y0) | ((unsigned int)f32_to_bf16(y1) << 16);
  }
}

extern "C" void kernel_launch(void* const* d_in, const int* in_sizes, int n_in,
                              void* d_out, int out_size, void* d_ws, size_t ws_size,
                              hipStream_t stream) {
  const float* h    = (const float*)d_in[0];
  const float* S0   = (const float*)d_in[1];
  const float* q_w  = (const float*)d_in[2];
  const float* k_w  = (const float*)d_in[3];
  const float* v_w  = (const float*)d_in[4];
  const float* f_w0 = (const float*)d_in[5];
  const float* f_w1 = (const float*)d_in[6];
  const float* b_w  = (const float*)d_in[7];
  const float* A_log  = (const float*)d_in[8];
  const float* dt_b   = (const float*)d_in[9];
  const float* g_w0 = (const float*)d_in[10];
  const float* g_w1 = (const float*)d_in[11];
  const float* g_b1 = (const float*)d_in[12];
  const float* o_nw = (const float*)d_in[13];
  const float* o_w  = (const float*)d_in[14];

  float* outp = (float*)d_out;                 // exp(g) -> factor -> final out
  float* Sout = outp + (size_t)8192 * 2048;

  const size_t BIG = (size_t)8192 * 2048;   // 16.8M elems
  float* ws = (float*)d_ws;
  float* vbuf  = ws;                         // f32 [BIG]
  float* qbuf  = vbuf + BIG;                 // f32 [BIG]; gated bf16 reuses this
  float* kbuf  = qbuf + BIG;                 // f32 [BIG]
  float* betab = kbuf + BIG;                 // f32 [8192*16]
  ushort_t* fpreb = (ushort_t*)(betab + (size_t)8192 * 16);   // bf16 [8192*128]
  ushort_t* gpreb = fpreb + (size_t)8192 * 128;
  ushort_t* wf1   = gpreb + (size_t)8192 * 128;               // [2048*128]
  ushort_t* wg1   = wf1 + (size_t)2048 * 128;
  ushort_t* wo    = wg1 + (size_t)2048 * 128;                 // [2048*2048]
  ushort_t* wlow  = wo + (size_t)2048 * 2048;                 // [384*2048]
  ushort_t* hb    = wlow + (size_t)384 * 2048;                // [BIG] bf16
  ushort_t* wqkv  = hb + BIG;                                 // [6144*2048] bf16
  // obuf (scan output, f32 BIG) aliases [hb | wqkv | pad] — all dead pre-scan
  float* obuf = (float*)hb;
  ushort_t* gatedb = (ushort_t*)qbuf;        // bf16 gated o (qbuf dead post-scan)

  const dim3 blk(256);

  // casts
  cast_bf16<<<16384, blk, 0, stream>>>(h, hb, 8192 * 2048);
  cast_bf16<<<4096, blk, 0, stream>>>(q_w, wqkv, 2048 * 2048);
  cast_bf16<<<4096, blk, 0, stream>>>(k_w, wqkv + (size_t)2048 * 2048, 2048 * 2048);
  cast_bf16<<<4096, blk, 0, stream>>>(v_w, wqkv + (size_t)4096 * 2048, 2048 * 2048);
  cast_bf16<<<4096, blk, 0, stream>>>(o_w, wo, 2048 * 2048);
  cast_bf16<<<256, blk, 0, stream>>>(f_w0, wlow, 128 * 2048);
  cast_bf16<<<256, blk, 0, stream>>>(g_w0, wlow + (size_t)128 * 2048, 128 * 2048);
  cast_bf16<<<32, blk, 0, stream>>>(b_w, wlow + (size_t)256 * 2048, 16 * 2048);
  cast_bf16<<<256, blk, 0, stream>>>(f_w1, wf1, 2048 * 128);
  cast_bf16<<<256, blk, 0, stream>>>(g_w1, wg1, 2048 * 128);

  // fused QKV projection: silu(+l2norm for q/k) -> qbuf/kbuf/vbuf f32
  gemm_bf16<<<dim3(48, 64), blk, 0, stream>>>(hb, wqkv, 8192, 6144, 2048, M_QKV,
      qbuf, kbuf, vbuf, nullptr, nullptr, nullptr, nullptr, nullptr);
  // fused lowrank: fpre|gpre (bf16) + beta (sigmoid f32)
  gemm_bf16<<<dim3(3, 64), blk, 0, stream>>>(hb, wlow, 8192, 384, 2048, M_LOWRANK,
      betab, nullptr, nullptr, fpreb, gpreb, nullptr, nullptr, nullptr);
  // exp(g) -> outp
  gemm_bf16<<<dim3(16, 64), blk, 0, stream>>>(fpreb, wf1, 8192, 2048, 128, M_GATE,
      outp, nullptr, nullptr, nullptr, nullptr, nullptr, A_log, dt_b);
  // scan: o -> obuf (hb/wqkv region dead), S -> d_out tail
  kda_scan<<<2048, 64, 0, stream>>>(qbuf, kbuf, vbuf, outp, betab, S0, obuf, Sout);
  // factor = gpre @ g_w1.T + g_b1 -> outp (exp(g) dead)
  gemm_bf16<<<dim3(16, 64), blk, 0, stream>>>(gpreb, wg1, 8192, 2048, 128, M_FACTOR,
      outp, nullptr, nullptr, nullptr, nullptr, g_b1, nullptr, nullptr);
  // gated rmsnorm -> bf16 into gatedb (qbuf region)
  gate_rmsnorm<<<2048, blk, 0, stream>>>(obuf, outp, o_nw, gatedb);
  // out = gated_o @ o_w.T -> outp
  gemm_bf16<<<dim3(16, 64), blk, 0, stream>>>(gatedb, wo, 8192, 2048, 2048, M_PLAIN,
      outp, nullptr, nullptr, nullptr, nullptr, nullptr, nullptr, nullptr);
}

// Round 4
// 1828.270 us; speedup vs baseline: 1.1937x; 1.0136x over previous
//
#include <hip/hip_runtime.h>
#include <math.h>

// ---------------------------------------------------------------------------
// KimiDeltaAttention B=4 T=2048 HID=2048 H=16 DK=DV=128
//  - one fused QKV bf16 MFMA GEMM (N=6144) with silu+l2norm in epilogue
//  - one fused lowrank GEMM (fpre|gpre|beta, N=384 padded)
//  - scan v8: v6 LDS-staged structure + all-SALU loop addressing (uniform
//    bases advanced in scalar code, fixed per-lane voffsets). Reduction uses
//    the update_dpp BUILTIN (v7's raw v_add_f32_dpp asm hit the VALU->DPP
//    2-wait-state hazard the compiler can't see inside asm -> corruption).
// ---------------------------------------------------------------------------

typedef short short8 __attribute__((ext_vector_type(8)));
typedef float f32x4 __attribute__((ext_vector_type(4)));
typedef unsigned short ushort_t;

// gemm epilogue modes
enum { M_PLAIN = 0, M_QKV = 1, M_LOWRANK = 2, M_GATE = 3, M_FACTOR = 4 };

__device__ __forceinline__ unsigned short f32_to_bf16(float f) {
  unsigned int u = __float_as_uint(f);
  u += 0x7FFFu + ((u >> 16) & 1u);   // RNE
  return (unsigned short)(u >> 16);
}

__device__ __forceinline__ float silu(float x) { return x / (1.f + __expf(-x)); }

__device__ __forceinline__ void gld_lds16(const void* g, void* l) {
  __builtin_amdgcn_global_load_lds(
      (const __attribute__((address_space(1))) unsigned int*)g,
      (__attribute__((address_space(3))) unsigned int*)l, 16, 0, 0);
}

// sum across each aligned 16-lane group, pure DPP (compiler handles hazards)
__device__ __forceinline__ float row16_sum(float x) {
  x += __int_as_float(__builtin_amdgcn_update_dpp(0, __float_as_int(x), 0xB1, 0xF, 0xF, true));
  x += __int_as_float(__builtin_amdgcn_update_dpp(0, __float_as_int(x), 0x4E, 0xF, 0xF, true));
  x += __int_as_float(__builtin_amdgcn_update_dpp(0, __float_as_int(x), 0x141, 0xF, 0xF, true));
  x += __int_as_float(__builtin_amdgcn_update_dpp(0, __float_as_int(x), 0x140, 0xF, 0xF, true));
  return x;
}

// ---------------------------------------------------------------------------
// bf16 MFMA GEMM, 128x128 tile, m97 structure + mode-switched epilogue.
// ---------------------------------------------------------------------------
__global__ __launch_bounds__(256) void gemm_bf16(
    const ushort_t* __restrict__ A, const ushort_t* __restrict__ W,
    int M, int N, int K, int mode,
    float* __restrict__ f0, float* __restrict__ f1, float* __restrict__ f2,
    ushort_t* __restrict__ b0, ushort_t* __restrict__ b1,
    const float* __restrict__ bias, const float* __restrict__ A_log,
    const float* __restrict__ dt_bias) {
  __shared__ alignas(16) ushort_t As[4096];
  __shared__ alignas(16) ushort_t Bs[4096];
  __shared__ float l2s[2][128];
  const int tid = threadIdx.x;
  const int wv = tid >> 6, ln = tid & 63;
  const int bm = blockIdx.y * 128, bn = blockIdx.x * 128;
  const int wm = wv >> 1, wn = wv & 1;

  const int srow = tid >> 2;
  const int skg = (tid & 3) ^ ((srow >> 1) & 3);
  const size_t ag0 = (size_t)(bm + srow) * K + skg * 8;
  const size_t ag1 = ag0 + (size_t)64 * K;
  const size_t bg0 = (size_t)(bn + srow) * K + skg * 8;
  const size_t bg1 = bg0 + (size_t)64 * K;
  char* const lA = (char*)As;
  char* const lB = (char*)Bs;
  const int wbase = wv * 1024;

  const int fr = ln & 15, fq = ln >> 4;
  const int pg = fq ^ ((fr >> 1) & 3);
  int aoff[4], boff[4];
#pragma unroll
  for (int i = 0; i < 4; i++) {
    aoff[i] = (wm * 64 + i * 16 + fr) * 64 + pg * 16;
    boff[i] = (wn * 64 + i * 16 + fr) * 64 + pg * 16;
  }

  f32x4 acc[4][4];
#pragma unroll
  for (int i = 0; i < 4; i++)
#pragma unroll
    for (int j = 0; j < 4; j++) {
      acc[i][j][0] = 0.f; acc[i][j][1] = 0.f; acc[i][j][2] = 0.f; acc[i][j][3] = 0.f;
    }

  for (int k0 = 0; k0 < K; k0 += 32) {
    gld_lds16(A + ag0 + k0, lA + wbase);
    gld_lds16(A + ag1 + k0, lA + 4096 + wbase);
    gld_lds16(W + bg0 + k0, lB + wbase);
    gld_lds16(W + bg1 + k0, lB + 4096 + wbase);
    __syncthreads();
    short8 af[4], bf[4];
#pragma unroll
    for (int i = 0; i < 4; i++) af[i] = *(const short8*)(lA + aoff[i]);
#pragma unroll
    for (int i = 0; i < 4; i++) bf[i] = *(const short8*)(lB + boff[i]);
#pragma unroll
    for (int i = 0; i < 4; i++)
#pragma unroll
      for (int j = 0; j < 4; j++)
        acc[i][j] = __builtin_amdgcn_mfma_f32_16x16x32_bf16(af[i], bf[j], acc[i][j], 0, 0, 0);
    __syncthreads();
  }

  // C/D layout: col = ln&15, row = (ln>>4)*4 + reg
  const int cc = ln & 15, cq = ln >> 4;

  if (mode == M_QKV) {
    // silu in place
#pragma unroll
    for (int i = 0; i < 4; i++)
#pragma unroll
      for (int j = 0; j < 4; j++)
#pragma unroll
        for (int r = 0; r < 4; r++) acc[i][j][r] = silu(acc[i][j][r]);
    const bool isqk = (bn < 4096);
    float invr[4][4];
    if (isqk) {
      const float scale = (bn < 2048) ? 0.08838834764831845f : 1.0f;
#pragma unroll
      for (int i = 0; i < 4; i++)
#pragma unroll
        for (int r = 0; r < 4; r++) {
          float ss = 0.f;
#pragma unroll
          for (int j = 0; j < 4; j++) ss = fmaf(acc[i][j][r], acc[i][j][r], ss);
          ss = row16_sum(ss);
          if (cc == 0) l2s[wn][wm * 64 + i * 16 + cq * 4 + r] = ss;
        }
      __syncthreads();
#pragma unroll
      for (int i = 0; i < 4; i++)
#pragma unroll
        for (int r = 0; r < 4; r++) {
          const int rl = wm * 64 + i * 16 + cq * 4 + r;
          invr[i][r] = rsqrtf(l2s[0][rl] + l2s[1][rl] + 1e-6f) * scale;
        }
    } else {
#pragma unroll
      for (int i = 0; i < 4; i++)
#pragma unroll
        for (int r = 0; r < 4; r++) invr[i][r] = 1.f;
    }
    float* dst = (bn < 2048) ? f0 : ((bn < 4096) ? f1 : f2);
    const int nb = bn & 2047;
#pragma unroll
    for (int i = 0; i < 4; i++)
#pragma unroll
      for (int r = 0; r < 4; r++) {
        const int gm = bm + wm * 64 + i * 16 + cq * 4 + r;
#pragma unroll
        for (int j = 0; j < 4; j++) {
          const int gn = nb + wn * 64 + j * 16 + cc;
          dst[(size_t)gm * 2048 + gn] = acc[i][j][r] * invr[i][r];
        }
      }
    return;
  }

  if (mode == M_LOWRANK) {
#pragma unroll
    for (int i = 0; i < 4; i++)
#pragma unroll
      for (int r = 0; r < 4; r++) {
        const int gm = bm + wm * 64 + i * 16 + cq * 4 + r;
#pragma unroll
        for (int j = 0; j < 4; j++) {
          const int gn = bn + wn * 64 + j * 16 + cc;
          const float x = acc[i][j][r];
          if (gn < 128) b0[(size_t)gm * 128 + gn] = f32_to_bf16(x);
          else if (gn < 256) b1[(size_t)gm * 128 + (gn - 128)] = f32_to_bf16(x);
          else if (gn < 272) f0[(size_t)gm * 16 + (gn - 256)] = 1.f / (1.f + __expf(-x));
        }
      }
    return;
  }

  // M_PLAIN / M_GATE / M_FACTOR -> f32, stride N
#pragma unroll
  for (int i = 0; i < 4; i++)
#pragma unroll
    for (int r = 0; r < 4; r++) {
      const int gm = bm + wm * 64 + i * 16 + cq * 4 + r;
#pragma unroll
      for (int j = 0; j < 4; j++) {
        const int gn = bn + wn * 64 + j * 16 + cc;
        float x = acc[i][j][r];
        if (mode == M_FACTOR) x += bias[gn];
        else if (mode == M_GATE) {
          const float y = x + dt_bias[gn];
          const float sp = fmaxf(y, 0.f) + log1pf(__expf(-fabsf(y)));
          x = __expf(-__expf(A_log[gn >> 7]) * sp);
        }
        f0[(size_t)gm * N + gn] = x;
      }
    }
}

__global__ __launch_bounds__(256) void cast_bf16(const float* __restrict__ x,
                                                 ushort_t* __restrict__ y, int n) {
  const int i = (blockIdx.x * 256 + threadIdx.x) * 4;
  if (i >= n) return;
  const float4 v = *(const float4*)&x[i];
  union { ushort_t u[4]; uint2 v2; } o;
  o.u[0] = f32_to_bf16(v.x); o.u[1] = f32_to_bf16(v.y);
  o.u[2] = f32_to_bf16(v.z); o.u[3] = f32_to_bf16(v.w);
  *(uint2*)&y[i] = o.v2;
}

// ---------------------------------------------------------------------------
// Barrier-free gated delta-rule scan, v8. LDS-staged k/q/g, all-SALU
// addressing, builtin-DPP reductions.
// grid = 2048 (64 bh x 32 colgroups, XCD-swizzled), block = 64 (one wave).
// Lane: cl = ln>>4 (4 cols), kg = ln&15 (16-way k-split), S[8]/lane.
// LDS: 4 slots x 3 streams x 1KB (2 steps/slot) = 12KB, 8-step horizon.
// All loop addresses: fixed per-lane voffset + uniform SGPR base advanced
// by scalar adds (zero VALU address arithmetic in the steady-state loop).
// ---------------------------------------------------------------------------
__global__ __launch_bounds__(64, 2) void kda_scan(
    const float* __restrict__ q, const float* __restrict__ k,
    const float* __restrict__ v, const float* __restrict__ ge,
    const float* __restrict__ beta, const float* __restrict__ S0,
    float* __restrict__ o, float* __restrict__ S_out) {
  const int bid = blockIdx.x;
  const int bh = (((bid >> 3) & 7) << 3) | (bid & 7);
  const int cg = bid >> 6;
  const int h = bh & 15, b = bh >> 4;
  const int ln = threadIdx.x;
  const int cl = ln >> 4, kg = ln & 15;
  const int col = cg * 4 + cl;
  const int kof = kg * 8;

  __shared__ alignas(16) char lds[12288];

  const size_t s_base = (size_t)bh * (128 * 128);
  const size_t rb = (size_t)b * (2048 * 2048) + (size_t)h * 128;
  const size_t bbase = (size_t)(b * 2048) * 16 + h;

  // uniform bases, advanced in SALU inside the loop
  const char* kc = (const char*)(k + rb);
  const char* qc = (const char*)(q + rb);
  const char* gc = (const char*)(ge + rb);
  const float* vbp  = v + rb;            // step-even v row
  const float* vbp2 = vbp + 2048;        // step-odd v row
  const float* bbp  = beta + bbase;
  const float* bbp2 = bbp + 16;
  float* obp  = o + rb;                  // step-even o row
  float* obp2 = obp + 2048;              // step-odd o row
  const float* S0b = S0 + s_base;

  // per-lane gld_lds SOURCE pre-swizzle (LDS dest is linear lane*16):
  // LDS chunk p holds global chunk g(p) = (p&~1)|((p&1)^((p>>3)&1))
  const int cpos = ln & 31;
  const int gch = (cpos & ~1) | ((cpos & 1) ^ ((cpos >> 3) & 1));
  const unsigned lane_src = (unsigned)((ln >> 5) * 8192 + gch * 16);

  // swizzled ds_read addresses for logical chunks q=0,1 of this lane's kg
  const unsigned rd0 = (unsigned)(kg * 32 + ((0 ^ ((kg >> 2) & 1)) * 16));
  const unsigned rd1 = (unsigned)(kg * 32 + ((1 ^ ((kg >> 2) & 1)) * 16));

  // fixed per-lane voffsets
  const unsigned voff_v = (unsigned)(col * 4);
  const unsigned voff_b = 0u;
  const unsigned voff_o = (unsigned)(col * 4);

  // ---- initial state via asm loads ----------------------------------------
  float S[8];
#pragma unroll
  for (int j = 0; j < 8; ++j) {
    const unsigned offs = (unsigned)(((kof + j) * 128 + col) * 4);
    asm volatile("global_load_dword %0, %1, %2" : "=v"(S[j]) : "v"(offs), "s"(S0b));
  }

  float Vs[8], Bs[8], Os[8];
  f32x4 K0a, K1a, Q0a, Q1a, G0a, G1a;
  f32x4 K0b, K1b, Q0b, Q1b, G0b, G1b;

#define WAITV(N) do { asm volatile("s_waitcnt vmcnt(" #N ")" ::: "memory"); \
                      __builtin_amdgcn_sched_barrier(0); } while (0)
#define WAITL(N) do { asm volatile("s_waitcnt lgkmcnt(" #N ")" ::: "memory"); \
                      __builtin_amdgcn_sched_barrier(0); } while (0)
#define DSR(dst, a, IMM) \
  asm volatile("ds_read_b128 %0, %1 offset:%c2" : "=v"(dst) : "v"(a), "n"(IMM))

// 6 ds_reads for one step: slot SL, phase PH, into buffer suffix SFX
#define READS(SFX, SL, PH)                                    \
  do {                                                        \
    DSR(K0##SFX, rd0, ((SL)*3 + 0) * 1024 + (PH)*512);        \
    DSR(K1##SFX, rd1, ((SL)*3 + 0) * 1024 + (PH)*512);        \
    DSR(Q0##SFX, rd0, ((SL)*3 + 1) * 1024 + (PH)*512);        \
    DSR(Q1##SFX, rd1, ((SL)*3 + 1) * 1024 + (PH)*512);        \
    DSR(G0##SFX, rd0, ((SL)*3 + 2) * 1024 + (PH)*512);        \
    DSR(G1##SFX, rd1, ((SL)*3 + 2) * 1024 + (PH)*512);        \
  } while (0)

// stage slot SL for the next 2 rows; 7 VMEM ops; bases advance via SALU
#define STAGE(SL)                                                                                    \
  do {                                                                                               \
    gld_lds16(kc + lane_src, lds + ((SL)*3 + 0) * 1024); kc += 16384;                                \
    gld_lds16(qc + lane_src, lds + ((SL)*3 + 1) * 1024); qc += 16384;                                \
    gld_lds16(gc + lane_src, lds + ((SL)*3 + 2) * 1024); gc += 16384;                                \
    asm volatile("global_load_dword %0, %1, %2" : "=v"(Vs[2*(SL)])   : "v"(voff_v), "s"(vbp));       \
    asm volatile("global_load_dword %0, %1, %2" : "=v"(Vs[2*(SL)+1]) : "v"(voff_v), "s"(vbp2));      \
    vbp += 4096; vbp2 += 4096;                                                                       \
    asm volatile("global_load_dword %0, %1, %2" : "=v"(Bs[2*(SL)])   : "v"(voff_b), "s"(bbp));       \
    asm volatile("global_load_dword %0, %1, %2" : "=v"(Bs[2*(SL)+1]) : "v"(voff_b), "s"(bbp2));      \
    bbp += 32; bbp2 += 32;                                                                           \
  } while (0)

#define STORES(U)                                                                                    \
  do {                                                                                               \
    if (kg == 0) {                                                                                   \
      asm volatile("global_store_dword %0, %1, %2" :: "v"(voff_o), "v"(Os[(U)-1]), "s"(obp) : "memory");  \
      asm volatile("global_store_dword %0, %1, %2" :: "v"(voff_o), "v"(Os[(U)]), "s"(obp2) : "memory");   \
    }                                                                                                \
    obp += 4096; obp2 += 4096;                                                                       \
  } while (0)

#define COMPUTE(SFX, U)                                                                              \
  do {                                                                                               \
    float p0 = 0.f, p1 = 0.f, o0 = 0.f, o1 = 0.f, d0 = 0.f, d1 = 0.f;                                \
    S[0] *= G0##SFX[0]; p0 = fmaf(K0##SFX[0], S[0], p0); o0 = fmaf(Q0##SFX[0], S[0], o0); d0 = fmaf(Q0##SFX[0], K0##SFX[0], d0); \
    S[1] *= G0##SFX[1]; p1 = fmaf(K0##SFX[1], S[1], p1); o1 = fmaf(Q0##SFX[1], S[1], o1); d1 = fmaf(Q0##SFX[1], K0##SFX[1], d1); \
    S[2] *= G0##SFX[2]; p0 = fmaf(K0##SFX[2], S[2], p0); o0 = fmaf(Q0##SFX[2], S[2], o0); d0 = fmaf(Q0##SFX[2], K0##SFX[2], d0); \
    S[3] *= G0##SFX[3]; p1 = fmaf(K0##SFX[3], S[3], p1); o1 = fmaf(Q0##SFX[3], S[3], o1); d1 = fmaf(Q0##SFX[3], K0##SFX[3], d1); \
    S[4] *= G1##SFX[0]; p0 = fmaf(K1##SFX[0], S[4], p0); o0 = fmaf(Q1##SFX[0], S[4], o0); d0 = fmaf(Q1##SFX[0], K1##SFX[0], d0); \
    S[5] *= G1##SFX[1]; p1 = fmaf(K1##SFX[1], S[5], p1); o1 = fmaf(Q1##SFX[1], S[5], o1); d1 = fmaf(Q1##SFX[1], K1##SFX[1], d1); \
    S[6] *= G1##SFX[2]; p0 = fmaf(K1##SFX[2], S[6], p0); o0 = fmaf(Q1##SFX[2], S[6], o0); d0 = fmaf(Q1##SFX[2], K1##SFX[2], d0); \
    S[7] *= G1##SFX[3]; p1 = fmaf(K1##SFX[3], S[7], p1); o1 = fmaf(Q1##SFX[3], S[7], o1); d1 = fmaf(Q1##SFX[3], K1##SFX[3], d1); \
    const float p  = row16_sum(p0 + p1);                                                             \
    const float oq = row16_sum(o0 + o1);                                                             \
    const float qk = row16_sum(d0 + d1);                                                             \
    const float delta = (Vs[(U)] - p) * Bs[(U)];                                                     \
    Os[(U)] = fmaf(qk, delta, oq);                                                                   \
    S[0] = fmaf(K0##SFX[0], delta, S[0]);                                                            \
    S[1] = fmaf(K0##SFX[1], delta, S[1]);                                                            \
    S[2] = fmaf(K0##SFX[2], delta, S[2]);                                                            \
    S[3] = fmaf(K0##SFX[3], delta, S[3]);                                                            \
    S[4] = fmaf(K1##SFX[0], delta, S[4]);                                                            \
    S[5] = fmaf(K1##SFX[1], delta, S[5]);                                                            \
    S[6] = fmaf(K1##SFX[2], delta, S[6]);                                                            \
    S[7] = fmaf(K1##SFX[3], delta, S[7]);                                                            \
  } while (0)

// even step U (slot SL): issue reads for U+1 (phase 1), compute U from 'a'
#define STEP_EVEN(U, SL) \
  do { READS(b, SL, 1); WAITL(6); COMPUTE(a, U); } while (0)
// odd step U (slot SL): wait, issue next-slot phase-0 reads, compute U from
// 'b', restage SL (+8 steps ahead), batch-store Os[U-1],Os[U]
#define STEP_ODD(U, SL, NSL, WV) \
  do { WAITV(WV); READS(a, NSL, 0); WAITL(6); COMPUTE(b, U); STAGE(SL); STORES(U); } while (0)

#define ITER(W1, W3, W5, W7)                          \
  do {                                                \
    STEP_EVEN(0, 0);                                  \
    STEP_ODD(1, 0, 1, W1);                            \
    STEP_EVEN(2, 1);                                  \
    STEP_ODD(3, 1, 2, W3);                            \
    STEP_EVEN(4, 2);                                  \
    STEP_ODD(5, 2, 3, W5);                            \
    STEP_EVEN(6, 3);                                  \
    STEP_ODD(7, 3, 0, W7);                            \
  } while (0)

  // ---- prologue: stage slots 0..3 (steps 0..7), wait slot0, prime reads ---
  STAGE(0);
  STAGE(1);
  STAGE(2);
  STAGE(3);
  WAITV(21);               // drains S0(8)+slot0(7); keeps slots 1-3 (21)
  READS(a, 0, 0);          // step 0 fragments

  ITER(14, 16, 18, 20);    // peeled first iteration (prologue FIFO spacing)
  for (int it = 1; it < 256; ++it) {
    ITER(20, 20, 20, 20);
  }
  // final iteration's restages/reads over-run into adjacent allocated
  // workspace/output regions (<=64KB) and are never consumed.

  // drain everything before the compiler may reuse destination VGPRs
  WAITL(0);
  WAITV(0);

#pragma unroll
  for (int j = 0; j < 8; ++j)
    S_out[s_base + (size_t)(kof + j) * 128 + col] = S[j];

#undef ITER
#undef STEP_ODD
#undef STEP_EVEN
#undef COMPUTE
#undef STORES
#undef STAGE
#undef READS
#undef DSR
#undef WAITL
#undef WAITV
}

// out_bf16 = rms(o)*w*sigmoid(factor). grid 2048 x 256: 64 rows/block.
__global__ __launch_bounds__(256) void gate_rmsnorm(
    const float* __restrict__ o, const float* __restrict__ factor,
    const float* __restrict__ w, ushort_t* __restrict__ out) {
  const int ln = threadIdx.x & 63, wv = threadIdx.x >> 6;
  const float w0 = w[ln * 2], w1 = w[ln * 2 + 1];
  const size_t row0 = (size_t)blockIdx.x * 64 + wv * 16;
  for (int it = 0; it < 16; it++) {
    const size_t base = (row0 + it) * 128 + ln * 2;
    const float2 x = *(const float2*)&o[base];
    const float2 f = *(const float2*)&factor[base];
    float ss = fmaf(x.x, x.x, x.y * x.y);
    ss = row16_sum(ss);
    ss += __shfl_xor(ss, 16);
    ss += __shfl_xor(ss, 32);
    const float r = rsqrtf(ss * (1.f / 128.f) + 1e-5f);
    const float y0 = x.x * r * w0 / (1.f + __expf(-f.x));
    const float y1 = x.y * r * w1 / (1.f + __expf(-f.y));
    *(unsigned int*)&out[base] =
        (unsigned int)f32_to_bf16(y0) | ((unsigned int)f32_to_bf16(y1) << 16);
  }
}

extern "C" void kernel_launch(void* const* d_in, const int* in_sizes, int n_in,
                              void* d_out, int out_size, void* d_ws, size_t ws_size,
                              hipStream_t stream) {
  const float* h    = (const float*)d_in[0];
  const float* S0   = (const float*)d_in[1];
  const float* q_w  = (const float*)d_in[2];
  const float* k_w  = (const float*)d_in[3];
  const float* v_w  = (const float*)d_in[4];
  const float* f_w0 = (const float*)d_in[5];
  const float* f_w1 = (const float*)d_in[6];
  const float* b_w  = (const float*)d_in[7];
  const float* A_log  = (const float*)d_in[8];
  const float* dt_b   = (const float*)d_in[9];
  const float* g_w0 = (const float*)d_in[10];
  const float* g_w1 = (const float*)d_in[11];
  const float* g_b1 = (const float*)d_in[12];
  const float* o_nw = (const float*)d_in[13];
  const float* o_w  = (const float*)d_in[14];

  float* outp = (float*)d_out;                 // exp(g) -> factor -> final out
  float* Sout = outp + (size_t)8192 * 2048;

  const size_t BIG = (size_t)8192 * 2048;   // 16.8M elems
  float* ws = (float*)d_ws;
  float* vbuf  = ws;                         // f32 [BIG]
  float* qbuf  = vbuf + BIG;                 // f32 [BIG]; gated bf16 reuses this
  float* kbuf  = qbuf + BIG;                 // f32 [BIG]
  float* betab = kbuf + BIG;                 // f32 [8192*16]
  ushort_t* fpreb = (ushort_t*)(betab + (size_t)8192 * 16);   // bf16 [8192*128]
  ushort_t* gpreb = fpreb + (size_t)8192 * 128;
  ushort_t* wf1   = gpreb + (size_t)8192 * 128;               // [2048*128]
  ushort_t* wg1   = wf1 + (size_t)2048 * 128;
  ushort_t* wo    = wg1 + (size_t)2048 * 128;                 // [2048*2048]
  ushort_t* wlow  = wo + (size_t)2048 * 2048;                 // [384*2048]
  ushort_t* hb    = wlow + (size_t)384 * 2048;                // [BIG] bf16
  ushort_t* wqkv  = hb + BIG;                                 // [6144*2048] bf16
  // obuf (scan output, f32 BIG) aliases [hb | wqkv | pad] — all dead pre-scan
  float* obuf = (float*)hb;
  ushort_t* gatedb = (ushort_t*)qbuf;        // bf16 gated o (qbuf dead post-scan)

  const dim3 blk(256);

  // casts
  cast_bf16<<<16384, blk, 0, stream>>>(h, hb, 8192 * 2048);
  cast_bf16<<<4096, blk, 0, stream>>>(q_w, wqkv, 2048 * 2048);
  cast_bf16<<<4096, blk, 0, stream>>>(k_w, wqkv + (size_t)2048 * 2048, 2048 * 2048);
  cast_bf16<<<4096, blk, 0, stream>>>(v_w, wqkv + (size_t)4096 * 2048, 2048 * 2048);
  cast_bf16<<<4096, blk, 0, stream>>>(o_w, wo, 2048 * 2048);
  cast_bf16<<<256, blk, 0, stream>>>(f_w0, wlow, 128 * 2048);
  cast_bf16<<<256, blk, 0, stream>>>(g_w0, wlow + (size_t)128 * 2048, 128 * 2048);
  cast_bf16<<<32, blk, 0, stream>>>(b_w, wlow + (size_t)256 * 2048, 16 * 2048);
  cast_bf16<<<256, blk, 0, stream>>>(f_w1, wf1, 2048 * 128);
  cast_bf16<<<256, blk, 0, stream>>>(g_w1, wg1, 2048 * 128);

  // fused QKV projection: silu(+l2norm for q/k) -> qbuf/kbuf/vbuf f32
  gemm_bf16<<<dim3(48, 64), blk, 0, stream>>>(hb, wqkv, 8192, 6144, 2048, M_QKV,
      qbuf, kbuf, vbuf, nullptr, nullptr, nullptr, nullptr, nullptr);
  // fused lowrank: fpre|gpre (bf16) + beta (sigmoid f32)
  gemm_bf16<<<dim3(3, 64), blk, 0, stream>>>(hb, wlow, 8192, 384, 2048, M_LOWRANK,
      betab, nullptr, nullptr, fpreb, gpreb, nullptr, nullptr, nullptr);
  // exp(g) -> outp
  gemm_bf16<<<dim3(16, 64), blk, 0, stream>>>(fpreb, wf1, 8192, 2048, 128, M_GATE,
      outp, nullptr, nullptr, nullptr, nullptr, nullptr, A_log, dt_b);
  // scan: o -> obuf (hb/wqkv region dead), S -> d_out tail
  kda_scan<<<2048, 64, 0, stream>>>(qbuf, kbuf, vbuf, outp, betab, S0, obuf, Sout);
  // factor = gpre @ g_w1.T + g_b1 -> outp (exp(g) dead)
  gemm_bf16<<<dim3(16, 64), blk, 0, stream>>>(gpreb, wg1, 8192, 2048, 128, M_FACTOR,
      outp, nullptr, nullptr, nullptr, nullptr, g_b1, nullptr, nullptr);
  // gated rmsnorm -> bf16 into gatedb (qbuf region)
  gate_rmsnorm<<<2048, blk, 0, stream>>>(obuf, outp, o_nw, gatedb);
  // out = gated_o @ o_w.T -> outp
  gemm_bf16<<<dim3(16, 64), blk, 0, stream>>>(gatedb, wo, 8192, 2048, 2048, M_PLAIN,
      outp, nullptr, nullptr, nullptr, nullptr, nullptr, nullptr, nullptr);
}